// Round 2
// 1098.654 us; speedup vs baseline: 1.0087x; 1.0087x over previous
//
#include <hip/hip_runtime.h>
#include <math.h>

// Problem: B=16, M=1024, N=1024 fp32; 20 ADMM iterations.
// RHO=1, LAMBD=0.1, ALPHA=0.5 -> threshold = 0.05, scale-const = 0.05.
//
// Fused persistent kernel (plain launch + manual grid barrier), with a
// host-side occupancy gate and a verbatim fallback to the proven
// multi-kernel version if co-residency cannot be guaranteed.
//
// State collapse: V_t = R_t + Z_{t-1} is the ONLY per-element state (VGPRs).
//   X_t = sc_t * softthr(V_t);  Z_t = V_t - X_t
//   R_{t+1} = normalize(sqrt(R0') * sqrt(X_t') * exp(-Z_t/2))
//   V_{t+1} = R_{t+1} + Z_t
// V >= 0 provably holds every iteration, so softthr(x) = fmaxf(x-THR, 0).
// Cross-block data per iteration: only the colsum cs (atomicAdd, device
// scope) -> read back with agent-scope atomic loads (XCD-L2 non-coherence).
#define NN 1024
#define NROWS 16384
#define TPB 256           // 4 waves/block
#define WPB 4
#define KSLOT 16
#define NIT 20

// fused config: 4 rows/wave -> 16 rows/block -> 1024 blocks (4/CU)
#define F_RPW 4
#define F_RPB (WPB * F_RPW)
#define F_NGRID (NROWS / F_RPB)   // 1024

// fallback config (R4-proven): 2 rows/wave -> 8 rows/block -> 2048 blocks
#define FB_RPW 2
#define FB_RPB (WPB * FB_RPW)
#define FB_NGRID (NROWS / FB_RPB) // 2048

#define MINV 1e-40f
#define THR  0.05f   // ALPHA*LAMBD/RHO
#define SCLC 0.05f   // (1-ALPHA)*LAMBD/RHO
#define EPSL 1e-10f

#define CS_BYTES ((size_t)NIT * KSLOT * NN * sizeof(float))

__device__ __forceinline__ float wred_sum(float v) {
#pragma unroll
  for (int o = 32; o > 0; o >>= 1) v += __shfl_xor(v, o, 64);
  return v;
}
__device__ __forceinline__ float softthr_full(float x) {
  return copysignf(fmaxf(fabsf(x) - THR, 0.0f), x);
}

// Monotonic-counter grid barrier: arrival #target releases everyone.
// Single address -> no load/RMW ordering hazard, no reset, no generations.
__device__ __forceinline__ void gbar(unsigned* bar, unsigned target) {
  __syncthreads();
  if (threadIdx.x == 0) {
    __threadfence();  // release my block's prior writes (atomics to cs)
    __hip_atomic_fetch_add(bar, 1u, __ATOMIC_ACQ_REL, __HIP_MEMORY_SCOPE_AGENT);
    while (__hip_atomic_load(bar, __ATOMIC_RELAXED, __HIP_MEMORY_SCOPE_AGENT) <
           target)
      __builtin_amdgcn_s_sleep(8);
    __threadfence();  // acquire side
  }
  __syncthreads();
}

// ============================ fused kernel =================================
// Layout: row = blockIdx.x*16 + wave*4 + rr; lane L covers cols {c*256+L*4+j}.
__global__ __launch_bounds__(TPB, 4) void k_fused(const float* __restrict__ R0,
                                                  float* __restrict__ OUT,
                                                  float* __restrict__ SQ,
                                                  float* __restrict__ cs,
                                                  unsigned* __restrict__ bar) {
  __shared__ float s_scale[NN];       // 4 KB
  __shared__ float s_part[WPB * NN];  // 16 KB  (20 KB total -> 4 blocks/CU)
  const int lane = threadIdx.x & 63;
  const int wv = threadIdx.x >> 6;
  const size_t row0 = (size_t)blockIdx.x * F_RPB + (size_t)wv * F_RPW;

  float V[F_RPW][16];  // persistent per-thread state (64 VGPRs)

  // ---- iter 0: V_1 = R0'/rowsum(R0'); SQ = sqrt(R0'); cs[0] += softthr^2.
#pragma unroll
  for (int rr = 0; rr < F_RPW; ++rr) {
    const size_t base = (row0 + rr) * NN + (size_t)lane * 4;
    float sloc = 0.f;
#pragma unroll
    for (int c = 0; c < 4; ++c) {
      const float4 r4 = *(const float4*)(R0 + base + c * 256);
      float* p = &V[rr][c * 4];
      p[0] = (r4.x == 0.f) ? MINV : r4.x;
      p[1] = (r4.y == 0.f) ? MINV : r4.y;
      p[2] = (r4.z == 0.f) ? MINV : r4.z;
      p[3] = (r4.w == 0.f) ? MINV : r4.w;
      sloc += (p[0] + p[1]) + (p[2] + p[3]);
      *(float4*)(SQ + base + c * 256) =
          make_float4(sqrtf(p[0]), sqrtf(p[1]), sqrtf(p[2]), sqrtf(p[3]));
    }
    const float inv = 1.0f / wred_sum(sloc);
#pragma unroll
    for (int c = 0; c < 4; ++c) {
      float a[4];
#pragma unroll
      for (int j = 0; j < 4; ++j) {
        const float rn = V[rr][c * 4 + j] * inv;  // V_1 = R_1 (Z_0 = 0)
        V[rr][c * 4 + j] = rn;
        const float s = fmaxf(rn - THR, 0.f);     // V >= 0
        a[j] = s * s;
      }
      float* sp = &s_part[wv * NN + c * 256 + lane * 4];
      if (rr == 0) {
        *(float4*)sp = make_float4(a[0], a[1], a[2], a[3]);
      } else {
        float4 o = *(float4*)sp;
        *(float4*)sp = make_float4(o.x + a[0], o.y + a[1], o.z + a[2], o.w + a[3]);
      }
    }
  }
  __syncthreads();
  {
    const int col = threadIdx.x * 4;
    const float4 s0 = *(float4*)(&s_part[0 * NN + col]);
    const float4 s1 = *(float4*)(&s_part[1 * NN + col]);
    const float4 s2 = *(float4*)(&s_part[2 * NN + col]);
    const float4 s3 = *(float4*)(&s_part[3 * NN + col]);
    float* dst = cs + (size_t)(blockIdx.x & (KSLOT - 1)) * NN + col;
    atomicAdd(dst + 0, (s0.x + s1.x) + (s2.x + s3.x));
    atomicAdd(dst + 1, (s0.y + s1.y) + (s2.y + s3.y));
    atomicAdd(dst + 2, (s0.z + s1.z) + (s2.z + s3.z));
    atomicAdd(dst + 3, (s0.w + s1.w) + (s2.w + s3.w));
  }
  gbar(bar, (unsigned)F_NGRID * 1u);

  // ---- iters t=1..19
#pragma unroll 1
  for (int t = 1; t < NIT; ++t) {
    const int last = (t == NIT - 1) ? 1 : 0;
    const float* csP = cs + (size_t)(t - 1) * KSLOT * NN;
    float* csN = cs + (size_t)t * KSLOT * NN;

    // Phase 0: scale[col] = max(1 - SCLC/(sqrt(sum_k cs[k][col]) + EPS), 0)
    // Agent-scope atomic loads: cs was written by other XCDs' atomics; plain
    // loads could hit stale zero lines in the local XCD L2.
    {
      const int col = threadIdx.x * 4;
      float ax = 0.f, ay = 0.f, az = 0.f, aw = 0.f;
#pragma unroll
      for (int k = 0; k < KSLOT; ++k) {
        const float* p = csP + (size_t)k * NN + col;
        ax += __hip_atomic_load(p + 0, __ATOMIC_RELAXED, __HIP_MEMORY_SCOPE_AGENT);
        ay += __hip_atomic_load(p + 1, __ATOMIC_RELAXED, __HIP_MEMORY_SCOPE_AGENT);
        az += __hip_atomic_load(p + 2, __ATOMIC_RELAXED, __HIP_MEMORY_SCOPE_AGENT);
        aw += __hip_atomic_load(p + 3, __ATOMIC_RELAXED, __HIP_MEMORY_SCOPE_AGENT);
      }
      s_scale[col + 0] = fmaxf(1.0f - SCLC / (sqrtf(ax) + EPSL), 0.0f);
      s_scale[col + 1] = fmaxf(1.0f - SCLC / (sqrtf(ay) + EPSL), 0.0f);
      s_scale[col + 2] = fmaxf(1.0f - SCLC / (sqrtf(az) + EPSL), 0.0f);
      s_scale[col + 3] = fmaxf(1.0f - SCLC / (sqrtf(aw) + EPSL), 0.0f);
    }
    __syncthreads();

#pragma unroll
    for (int rr = 0; rr < F_RPW; ++rr) {
      const size_t base = (row0 + rr) * NN + (size_t)lane * 4;
      float u[16];
      float sloc = 0.f;
#pragma unroll
      for (int c = 0; c < 4; ++c) {
        const float4 sq4 = *(const float4*)(SQ + base + c * 256);
        const float4 sc4 = *(const float4*)(&s_scale[c * 256 + lane * 4]);
        const float sq[4] = {sq4.x, sq4.y, sq4.z, sq4.w};
        const float sc[4] = {sc4.x, sc4.y, sc4.z, sc4.w};
#pragma unroll
        for (int j = 0; j < 4; ++j) {
          const float vv = V[rr][c * 4 + j];
          const float s = fmaxf(vv - THR, 0.f);   // softthr, V>=0
          const float X = sc[j] * s;              // X_t (never stored)
          const float zz = vv - X;                // Z_t
          const float Xm = (X == 0.f) ? MINV : X;
          const float uu = sq[j] * sqrtf(Xm) * __expf(-0.5f * zz);
          u[c * 4 + j] = uu;
          V[rr][c * 4 + j] = zz;                  // state slot now holds z
          sloc += uu;
        }
      }
      const float inv = 1.0f / wred_sum(sloc);
      if (!last) {
#pragma unroll
        for (int c = 0; c < 4; ++c) {
          float a[4];
#pragma unroll
          for (int j = 0; j < 4; ++j) {
            const float nv = u[c * 4 + j] * inv + V[rr][c * 4 + j];  // R+z
            V[rr][c * 4 + j] = nv;               // V_{t+1}
            const float s = fmaxf(nv - THR, 0.f);
            a[j] = s * s;
          }
          float* sp = &s_part[wv * NN + c * 256 + lane * 4];
          if (rr == 0) {
            *(float4*)sp = make_float4(a[0], a[1], a[2], a[3]);
          } else {
            float4 o = *(float4*)sp;
            *(float4*)sp =
                make_float4(o.x + a[0], o.y + a[1], o.z + a[2], o.w + a[3]);
          }
        }
      } else {
#pragma unroll
        for (int c = 0; c < 4; ++c) {
          *(float4*)(OUT + base + c * 256) =
              make_float4(u[c * 4 + 0] * inv, u[c * 4 + 1] * inv,
                          u[c * 4 + 2] * inv, u[c * 4 + 3] * inv);  // R_20
        }
      }
    }

    if (!last) {
      __syncthreads();
      {
        const int col = threadIdx.x * 4;
        const float4 s0 = *(float4*)(&s_part[0 * NN + col]);
        const float4 s1 = *(float4*)(&s_part[1 * NN + col]);
        const float4 s2 = *(float4*)(&s_part[2 * NN + col]);
        const float4 s3 = *(float4*)(&s_part[3 * NN + col]);
        float* dst = csN + (size_t)(blockIdx.x & (KSLOT - 1)) * NN + col;
        atomicAdd(dst + 0, (s0.x + s1.x) + (s2.x + s3.x));
        atomicAdd(dst + 1, (s0.y + s1.y) + (s2.y + s3.y));
        atomicAdd(dst + 2, (s0.z + s1.z) + (s2.z + s3.z));
        atomicAdd(dst + 3, (s0.w + s1.w) + (s2.w + s3.w));
      }
      gbar(bar, (unsigned)F_NGRID * (unsigned)(t + 1));
    }
  }
}

// ======================= fallback (R4-proven, 1108 µs) =====================
__global__ __launch_bounds__(TPB) void k_start(const float* __restrict__ R0,
                                               float* __restrict__ V,
                                               float* __restrict__ SQ,
                                               float* __restrict__ cs0) {
  __shared__ float s_part[WPB * NN];
  const int lane = threadIdx.x & 63;
  const int wv = threadIdx.x >> 6;
#pragma unroll
  for (int rr = 0; rr < FB_RPW; ++rr) {
    const size_t row = (size_t)blockIdx.x * FB_RPB + wv * FB_RPW + rr;
    const size_t base = row * NN + (size_t)lane * 4;
    float r0v[16];
    float sloc = 0.f;
#pragma unroll
    for (int c = 0; c < 4; ++c) {
      const float4 r4 = *(const float4*)(R0 + base + c * 256);
      float* p = &r0v[c * 4];
      p[0] = (r4.x == 0.f) ? MINV : r4.x;
      p[1] = (r4.y == 0.f) ? MINV : r4.y;
      p[2] = (r4.z == 0.f) ? MINV : r4.z;
      p[3] = (r4.w == 0.f) ? MINV : r4.w;
      sloc += (p[0] + p[1]) + (p[2] + p[3]);
      *(float4*)(SQ + base + c * 256) =
          make_float4(sqrtf(p[0]), sqrtf(p[1]), sqrtf(p[2]), sqrtf(p[3]));
    }
    const float inv = 1.0f / wred_sum(sloc);
#pragma unroll
    for (int c = 0; c < 4; ++c) {
      float rn[4], a[4];
#pragma unroll
      for (int j = 0; j < 4; ++j) {
        rn[j] = r0v[c * 4 + j] * inv;
        const float s = softthr_full(rn[j]);
        a[j] = s * s;
      }
      *(float4*)(V + base + c * 256) = make_float4(rn[0], rn[1], rn[2], rn[3]);
      float* sp = &s_part[wv * NN + c * 256 + lane * 4];
      if (rr == 0) {
        *(float4*)sp = make_float4(a[0], a[1], a[2], a[3]);
      } else {
        float4 o = *(float4*)sp;
        *(float4*)sp = make_float4(o.x + a[0], o.y + a[1], o.z + a[2], o.w + a[3]);
      }
    }
  }
  __syncthreads();
  const int col = threadIdx.x * 4;
  const float4 s0 = *(float4*)(&s_part[0 * NN + col]);
  const float4 s1 = *(float4*)(&s_part[1 * NN + col]);
  const float4 s2 = *(float4*)(&s_part[2 * NN + col]);
  const float4 s3 = *(float4*)(&s_part[3 * NN + col]);
  float* dst = cs0 + (size_t)(blockIdx.x & (KSLOT - 1)) * NN + col;
  atomicAdd(dst + 0, (s0.x + s1.x) + (s2.x + s3.x));
  atomicAdd(dst + 1, (s0.y + s1.y) + (s2.y + s3.y));
  atomicAdd(dst + 2, (s0.z + s1.z) + (s2.z + s3.z));
  atomicAdd(dst + 3, (s0.w + s1.w) + (s2.w + s3.w));
}

__global__ __launch_bounds__(TPB) void k_ab(float* __restrict__ V,
                                            const float* __restrict__ SQ,
                                            const float* __restrict__ csPrev,
                                            float* __restrict__ csNext,
                                            int last) {
  __shared__ float s_scale[NN];
  __shared__ float s_part[WPB * NN];
  const int lane = threadIdx.x & 63;
  const int wv = threadIdx.x >> 6;
  {
    const int col = threadIdx.x * 4;
    float4 a = make_float4(0.f, 0.f, 0.f, 0.f);
#pragma unroll
    for (int k = 0; k < KSLOT; ++k) {
      const float4 v = *(const float4*)(csPrev + (size_t)k * NN + col);
      a.x += v.x; a.y += v.y; a.z += v.z; a.w += v.w;
    }
    s_scale[col + 0] = fmaxf(1.0f - SCLC / (sqrtf(a.x) + EPSL), 0.0f);
    s_scale[col + 1] = fmaxf(1.0f - SCLC / (sqrtf(a.y) + EPSL), 0.0f);
    s_scale[col + 2] = fmaxf(1.0f - SCLC / (sqrtf(a.z) + EPSL), 0.0f);
    s_scale[col + 3] = fmaxf(1.0f - SCLC / (sqrtf(a.w) + EPSL), 0.0f);
  }
  __syncthreads();

#pragma unroll
  for (int rr = 0; rr < FB_RPW; ++rr) {
    const size_t row = (size_t)blockIdx.x * FB_RPB + wv * FB_RPW + rr;
    const size_t base = row * NN + (size_t)lane * 4;
    float u[16], z[16];
    float sloc = 0.f;
#pragma unroll
    for (int c = 0; c < 4; ++c) {
      const float4 vv4 = *(const float4*)(V + base + c * 256);
      const float4 sq4 = *(const float4*)(SQ + base + c * 256);
      const float4 sc4 = *(const float4*)(&s_scale[c * 256 + lane * 4]);
      const float vv[4] = {vv4.x, vv4.y, vv4.z, vv4.w};
      const float sq[4] = {sq4.x, sq4.y, sq4.z, sq4.w};
      const float sc[4] = {sc4.x, sc4.y, sc4.z, sc4.w};
#pragma unroll
      for (int j = 0; j < 4; ++j) {
        const float s = softthr_full(vv[j]);
        const float X = sc[j] * s;
        const float zz = vv[j] - X;
        z[c * 4 + j] = zz;
        const float Xm = (X == 0.f) ? MINV : X;
        const float uu = sq[j] * sqrtf(Xm) * __expf(-0.5f * zz);
        u[c * 4 + j] = uu;
        sloc += uu;
      }
    }
    const float inv = 1.0f / wred_sum(sloc);
#pragma unroll
    for (int c = 0; c < 4; ++c) {
      float outv[4];
#pragma unroll
      for (int j = 0; j < 4; ++j) {
        const float rn = u[c * 4 + j] * inv;
        outv[j] = last ? rn : (rn + z[c * 4 + j]);
      }
      *(float4*)(V + base + c * 256) =
          make_float4(outv[0], outv[1], outv[2], outv[3]);
      if (!last) {
        float a[4];
#pragma unroll
        for (int j = 0; j < 4; ++j) {
          const float s = softthr_full(outv[j]);
          a[j] = s * s;
        }
        float* sp = &s_part[wv * NN + c * 256 + lane * 4];
        if (rr == 0) {
          *(float4*)sp = make_float4(a[0], a[1], a[2], a[3]);
        } else {
          float4 o = *(float4*)sp;
          *(float4*)sp =
              make_float4(o.x + a[0], o.y + a[1], o.z + a[2], o.w + a[3]);
        }
      }
    }
  }
  if (!last) {
    __syncthreads();
    const int col = threadIdx.x * 4;
    const float4 s0 = *(float4*)(&s_part[0 * NN + col]);
    const float4 s1 = *(float4*)(&s_part[1 * NN + col]);
    const float4 s2 = *(float4*)(&s_part[2 * NN + col]);
    const float4 s3 = *(float4*)(&s_part[3 * NN + col]);
    float* dst = csNext + (size_t)(blockIdx.x & (KSLOT - 1)) * NN + col;
    atomicAdd(dst + 0, (s0.x + s1.x) + (s2.x + s3.x));
    atomicAdd(dst + 1, (s0.y + s1.y) + (s2.y + s3.y));
    atomicAdd(dst + 2, (s0.z + s1.z) + (s2.z + s3.z));
    atomicAdd(dst + 3, (s0.w + s1.w) + (s2.w + s3.w));
  }
}

extern "C" void kernel_launch(void* const* d_in, const int* in_sizes, int n_in,
                              void* d_out, int out_size, void* d_ws, size_t ws_size,
                              hipStream_t stream) {
  (void)in_sizes; (void)n_in; (void)out_size; (void)ws_size;
  const float* R0 = (const float*)d_in[0];
  float* OUT = (float*)d_out;
  float* SQ = (float*)d_ws;   // 64 MB: sqrt(R0'), iteration-invariant
  float* cs = (float*)((char*)d_ws + (size_t)NROWS * NN * sizeof(float));
  unsigned* bar = (unsigned*)((char*)cs + CS_BYTES);

  // Co-residency gate: fused persistent kernel only if all 1024 blocks fit.
  static int mode = -1;
  if (mode < 0) {
    mode = 0;
    int dev = 0, ncu = 0, maxb = 0;
    if (hipGetDevice(&dev) == hipSuccess &&
        hipDeviceGetAttribute(&ncu, hipDeviceAttributeMultiprocessorCount,
                              dev) == hipSuccess &&
        hipOccupancyMaxActiveBlocksPerMultiprocessor(&maxb, k_fused, TPB, 0) ==
            hipSuccess) {
      if ((long)maxb * (long)ncu >= (long)F_NGRID) mode = 1;
    }
  }

  hipMemsetAsync(cs, 0, CS_BYTES + 64, stream);  // cs slices + barrier counter
  if (mode == 1) {
    k_fused<<<F_NGRID, TPB, 0, stream>>>(R0, OUT, SQ, cs, bar);
  } else {
    k_start<<<FB_NGRID, TPB, 0, stream>>>(R0, OUT, SQ, cs);
    for (int it = 1; it < NIT; ++it) {
      k_ab<<<FB_NGRID, TPB, 0, stream>>>(OUT, SQ,
                                         cs + (size_t)(it - 1) * KSLOT * NN,
                                         cs + (size_t)it * KSLOT * NN,
                                         (it == NIT - 1) ? 1 : 0);
    }
  }
}